// Round 2
// baseline (600.667 us; speedup 1.0000x reference)
//
#include <hip/hip_runtime.h>
#include <hip/hip_bf16.h>

#define IN_CH 128
#define H1C1  32    // heads1 * c1
#define NH1   4
#define OUTC  64
#define NEG   0.2f

typedef __hip_bfloat16 bf16;
__device__ __forceinline__ float b2f(bf16 v) { return __bfloat162float(v); }

// ---------------- CSR build ----------------

__global__ void k_init_cnt(int* cnt, int n) {
  int i = blockIdx.x * blockDim.x + threadIdx.x;
  if (i < n) cnt[i] = 1;   // self-loop pre-count
}

__global__ void k_hist(const int* __restrict__ ei, int* cnt, int E, int n) {
  int e = blockIdx.x * blockDim.x + threadIdx.x;
  if (e < E) {
    int d = ei[E + e];                 // dst
    d = d < 0 ? 0 : (d >= n ? n - 1 : d);
    atomicAdd(&cnt[d], 1);
  }
}

// exclusive scan of cnt[0..n) -> rowptr[0..n], single block of 1024
__global__ __launch_bounds__(1024) void k_scan(const int* __restrict__ cnt,
                                               int* __restrict__ rowptr, int n) {
  __shared__ int wsum[16];
  __shared__ int carry_s;
  int t = threadIdx.x;
  int lane = t & 63, wid = t >> 6;
  if (t == 0) carry_s = 0;
  __syncthreads();
  for (int base = 0; base < n; base += 1024) {
    int i = base + t;
    int v = (i < n) ? cnt[i] : 0;
    int orig = v;
    for (int off = 1; off < 64; off <<= 1) {
      int u = __shfl_up(v, off, 64);
      if (lane >= off) v += u;
    }
    if (lane == 63) wsum[wid] = v;
    __syncthreads();
    if (wid == 0) {
      int s = (lane < 16) ? wsum[lane] : 0;
      for (int off = 1; off < 16; off <<= 1) {
        int u = __shfl_up(s, off, 64);
        if (lane >= off) s += u;
      }
      if (lane < 16) wsum[lane] = s;   // inclusive wave-sums
    }
    __syncthreads();
    int woff = (wid > 0) ? wsum[wid - 1] : 0;
    int incl = v + woff;
    int c = carry_s;
    if (i < n) rowptr[i] = c + incl - orig;   // exclusive
    __syncthreads();
    if (t == 0) carry_s = c + wsum[15];
    __syncthreads();
  }
  if (t == 0) rowptr[n] = carry_s;
}

__global__ void k_scatter(const int* __restrict__ ei, const int* __restrict__ rowptr,
                          int* cur, int* __restrict__ col, int E, int n) {
  int e = blockIdx.x * blockDim.x + threadIdx.x;
  int i, j;
  if (e < E) {
    j = ei[e];
    i = ei[E + e];
    j = j < 0 ? 0 : (j >= n ? n - 1 : j);
    i = i < 0 ? 0 : (i >= n ? n - 1 : i);
  } else if (e < E + n) {
    i = j = e - E;          // self-loop
  } else {
    return;
  }
  int pos = atomicAdd(&cur[i], 1);
  col[rowptr[i] + pos] = j;
}

// ---------------- layer 1: node transform ----------------
// h1 = x @ W1 (128->32); a_src1/a_dst1 per (node, head)
__global__ __launch_bounds__(256) void k_l1_transform(
    const float* __restrict__ x, const float* __restrict__ W1,
    const float* __restrict__ as1, const float* __restrict__ ad1,
    float* __restrict__ h1, float* __restrict__ a_src, float* __restrict__ a_dst,
    int n) {
  __shared__ float W1s[IN_CH * H1C1];   // 16 KB, [k*32+m]
  __shared__ float xs[8 * IN_CH];       // 4 KB
  int t = threadIdx.x;
  for (int idx = t; idx < IN_CH * H1C1; idx += 256) W1s[idx] = W1[idx];
  int base = blockIdx.x * 8;
  for (int idx = t; idx < 8 * IN_CH; idx += 256) {
    int row = idx >> 7, k = idx & 127;
    int nb = base + row;
    xs[idx] = (nb < n) ? x[(size_t)nb * IN_CH + k] : 0.f;
  }
  __syncthreads();
  int nl = t >> 5, m = t & 31;          // m = hd*8 + c
  int node = base + nl;
  float acc = 0.f;
#pragma unroll
  for (int k = 0; k < IN_CH; k++) acc += xs[nl * IN_CH + k] * W1s[k * H1C1 + m];
  float vs = acc * as1[m];
  float vd = acc * ad1[m];
  // reduce over c (8 lanes, aligned groups)
  for (int off = 1; off < 8; off <<= 1) {
    vs += __shfl_xor(vs, off, 64);
    vd += __shfl_xor(vd, off, 64);
  }
  if (node < n) {
    h1[(size_t)node * H1C1 + m] = acc;
    if ((m & 7) == 0) {
      a_src[node * NH1 + (m >> 3)] = vs;
      a_dst[node * NH1 + (m >> 3)] = vd;
    }
  }
}

// ---------------- layer 1: aggregate ----------------
// one wave per node; lanes 0..31 = (head,ch), halves process alternate edges
__global__ __launch_bounds__(256) void k_l1_agg(
    const int* __restrict__ rowptr, const int* __restrict__ col,
    const float* __restrict__ h1, const float* __restrict__ a_src,
    const float* __restrict__ a_dst, const float* __restrict__ b1,
    float* __restrict__ h1out, int n) {
  int wid = threadIdx.x >> 6, lane = threadIdx.x & 63;
  int node = blockIdx.x * 4 + wid;
  if (node >= n) return;
  int idx = lane & 31;
  int hd = idx >> 3;
  int half = lane >> 5;
  int rs = rowptr[node], re = rowptr[node + 1];
  float adst = a_dst[node * NH1 + hd];
  float acc = 0.f, sw = 0.f;
  for (int e = rs + half; e < re; e += 2) {
    int j = col[e];
    float lg = a_src[j * NH1 + hd] + adst;
    lg = lg > 0.f ? lg : NEG * lg;
    float w = __expf(lg);
    sw += w;
    acc += w * h1[(size_t)j * H1C1 + idx];
  }
  acc += __shfl_down(acc, 32, 64);
  sw  += __shfl_down(sw, 32, 64);
  if (half == 0) {
    float o = acc / (sw + 1e-16f) + b1[idx];
    h1out[(size_t)node * H1C1 + idx] = fmaxf(o, 0.f);   // relu between layers
  }
}

// ---------------- layer 2: node transform ----------------
// h2 = h1out @ W2 (32->64), stored bf16 (internal); a_src2/a_dst2 per node
__global__ __launch_bounds__(256) void k_l2_transform(
    const float* __restrict__ h1out, const float* __restrict__ W2,
    const float* __restrict__ as2, const float* __restrict__ ad2,
    bf16* __restrict__ h2, float* __restrict__ a_src2, float* __restrict__ a_dst2,
    int n) {
  __shared__ float W2s[H1C1 * OUTC];   // 8 KB, [k*64+c]
  __shared__ float hs[4 * H1C1];
  int t = threadIdx.x;
  for (int idx = t; idx < H1C1 * OUTC; idx += 256) W2s[idx] = W2[idx];
  int base = blockIdx.x * 4;
  if (t < 4 * H1C1) {
    int row = t >> 5, k = t & 31;
    int nb = base + row;
    hs[t] = (nb < n) ? h1out[(size_t)nb * H1C1 + k] : 0.f;
  }
  __syncthreads();
  int nl = t >> 6, c = t & 63;
  int node = base + nl;
  float acc = 0.f;
#pragma unroll
  for (int k = 0; k < H1C1; k++) acc += hs[nl * H1C1 + k] * W2s[k * OUTC + c];
  float vs = acc * as2[c];
  float vd = acc * ad2[c];
  for (int off = 1; off < 64; off <<= 1) {
    vs += __shfl_xor(vs, off, 64);
    vd += __shfl_xor(vd, off, 64);
  }
  if (node < n) {
    h2[(size_t)node * OUTC + c] = __float2bfloat16(acc);
    if (c == 0) { a_src2[node] = vs; a_dst2[node] = vd; }
  }
}

// ---------------- layer 2: aggregate + output (fp32) ----------------
__global__ __launch_bounds__(256) void k_l2_agg(
    const int* __restrict__ rowptr, const int* __restrict__ col,
    const bf16* __restrict__ h2, const float* __restrict__ a_src2,
    const float* __restrict__ a_dst2, const float* __restrict__ b2v,
    float* __restrict__ out, int n) {
  int wid = threadIdx.x >> 6, lane = threadIdx.x & 63;
  int node = blockIdx.x * 4 + wid;
  if (node >= n) return;
  int rs = rowptr[node], re = rowptr[node + 1];
  float adst = a_dst2[node];
  float acc = 0.f, sw = 0.f;
  for (int e = rs; e < re; e++) {
    int j = col[e];
    float lg = a_src2[j] + adst;
    lg = lg > 0.f ? lg : NEG * lg;
    float w = __expf(lg);
    sw += w;
    acc += w * b2f(h2[(size_t)j * OUTC + lane]);
  }
  float o = acc / (sw + 1e-16f) + b2v[lane];
  out[(size_t)node * OUTC + lane] = o;
}

// ---------------- launch ----------------

extern "C" void kernel_launch(void* const* d_in, const int* in_sizes, int n_in,
                              void* d_out, int out_size, void* d_ws, size_t ws_size,
                              hipStream_t stream) {
  const float* x   = (const float*)d_in[0];
  const int*   ei  = (const int*)d_in[1];
  const float* W1  = (const float*)d_in[2];
  const float* as1 = (const float*)d_in[3];
  const float* ad1 = (const float*)d_in[4];
  const float* b1  = (const float*)d_in[5];
  const float* W2  = (const float*)d_in[6];
  const float* as2 = (const float*)d_in[7];
  const float* ad2 = (const float*)d_in[8];
  const float* b2  = (const float*)d_in[9];
  float* out = (float*)d_out;

  int n = in_sizes[0] / IN_CH;   // 50000
  int E = in_sizes[1] / 2;       // 1600000

  // Workspace with phase aliasing (peak ~21.4 MB):
  //  [cnt|cur][rowptr][col][h1out][D: h1+a_src1+a_dst1  /  h2+a_src2+a_dst2]
  char* w = (char*)d_ws;
  auto al = [](size_t v) { return (v + 255) & ~(size_t)255; };
  size_t off = 0;
  int*   cnt    = (int*)(w + off); off += al((size_t)n * 4);        // reused as cur
  int*   rowptr = (int*)(w + off); off += al((size_t)(n + 1) * 4);
  int*   col    = (int*)(w + off); off += al((size_t)(E + n) * 4);
  float* h1out  = (float*)(w + off); off += al((size_t)n * H1C1 * 4);
  size_t dyn = off;
  // phase 1
  float* h1     = (float*)(w + dyn);
  float* a_src1 = (float*)(w + dyn + al((size_t)n * H1C1 * 4));
  float* a_dst1 = (float*)(w + dyn + al((size_t)n * H1C1 * 4) + al((size_t)n * NH1 * 4));
  // phase 2 (aliases phase-1 region; h1/a_src1/a_dst1 dead by then)
  bf16*  h2     = (bf16*)(w + dyn);
  float* a_src2 = (float*)(w + dyn + al((size_t)n * OUTC * 2));
  float* a_dst2 = (float*)(w + dyn + al((size_t)n * OUTC * 2) + al((size_t)n * 4));
  int*   cur    = cnt;   // cnt dead after k_scan

  // CSR build (shared by both layers)
  hipLaunchKernelGGL(k_init_cnt, dim3((n + 255) / 256), dim3(256), 0, stream, cnt, n);
  hipLaunchKernelGGL(k_hist, dim3((E + 255) / 256), dim3(256), 0, stream, ei, cnt, E, n);
  hipLaunchKernelGGL(k_scan, dim3(1), dim3(1024), 0, stream, cnt, rowptr, n);
  hipMemsetAsync(cur, 0, (size_t)n * 4, stream);
  hipLaunchKernelGGL(k_scatter, dim3((E + n + 255) / 256), dim3(256), 0, stream,
                     ei, rowptr, cur, col, E, n);

  // layer 1
  hipLaunchKernelGGL(k_l1_transform, dim3((n + 7) / 8), dim3(256), 0, stream,
                     x, W1, as1, ad1, h1, a_src1, a_dst1, n);
  hipLaunchKernelGGL(k_l1_agg, dim3((n + 3) / 4), dim3(256), 0, stream,
                     rowptr, col, h1, a_src1, a_dst1, b1, h1out, n);

  // layer 2
  hipLaunchKernelGGL(k_l2_transform, dim3((n + 3) / 4), dim3(256), 0, stream,
                     h1out, W2, as2, ad2, h2, a_src2, a_dst2, n);
  hipLaunchKernelGGL(k_l2_agg, dim3((n + 3) / 4), dim3(256), 0, stream,
                     rowptr, col, h2, a_src2, a_dst2, b2, out, n);
}

// Round 3
// 441.066 us; speedup vs baseline: 1.3619x; 1.3619x over previous
//
#include <hip/hip_runtime.h>
#include <hip/hip_bf16.h>

#define IN_CH 128
#define H1C1  32    // heads1 * c1
#define NH1   4
#define OUTC  64
#define NEG   0.2f
#define RPAD  8     // CSR row padding (multiple of, for int4 loads + ILP)

typedef __hip_bfloat16 bf16;
__device__ __forceinline__ float b2f(bf16 v) { return __bfloat162float(v); }

// ---------------- CSR build ----------------

__global__ void k_init_cnt(int* cnt, int n) {
  int i = blockIdx.x * blockDim.x + threadIdx.x;
  if (i < n) cnt[i] = 1;   // self-loop pre-count
}

__global__ void k_hist(const int* __restrict__ ei, int* cnt, int E, int n) {
  int e = blockIdx.x * blockDim.x + threadIdx.x;
  if (e < E) {
    int d = ei[E + e];                 // dst
    d = d < 0 ? 0 : (d >= n ? n - 1 : d);
    atomicAdd(&cnt[d], 1);
  }
}

// exclusive scan of padded degrees -> rowptr[0..n], single block of 1024
__global__ __launch_bounds__(1024) void k_scan(const int* __restrict__ cnt,
                                               int* __restrict__ rowptr, int n) {
  __shared__ int wsum[16];
  __shared__ int carry_s;
  int t = threadIdx.x;
  int lane = t & 63, wid = t >> 6;
  if (t == 0) carry_s = 0;
  __syncthreads();
  for (int base = 0; base < n; base += 1024) {
    int i = base + t;
    int v = (i < n) ? ((cnt[i] + RPAD - 1) & ~(RPAD - 1)) : 0;  // pad row to 8
    int orig = v;
    for (int off = 1; off < 64; off <<= 1) {
      int u = __shfl_up(v, off, 64);
      if (lane >= off) v += u;
    }
    if (lane == 63) wsum[wid] = v;
    __syncthreads();
    if (wid == 0) {
      int s = (lane < 16) ? wsum[lane] : 0;
      for (int off = 1; off < 16; off <<= 1) {
        int u = __shfl_up(s, off, 64);
        if (lane >= off) s += u;
      }
      if (lane < 16) wsum[lane] = s;
    }
    __syncthreads();
    int woff = (wid > 0) ? wsum[wid - 1] : 0;
    int incl = v + woff;
    int c = carry_s;
    if (i < n) rowptr[i] = c + incl - orig;   // exclusive
    __syncthreads();
    if (t == 0) carry_s = c + wsum[15];
    __syncthreads();
  }
  if (t == 0) rowptr[n] = carry_s;
}

// fill col with sentinel node id n (padding slots keep it)
__global__ void k_fill_col(int* __restrict__ col, int total, int n) {
  int i = blockIdx.x * blockDim.x + threadIdx.x;
  if (i < total) col[i] = n;
}

__global__ void k_scatter(const int* __restrict__ ei, const int* __restrict__ rowptr,
                          int* cur, int* __restrict__ col, int E, int n) {
  int e = blockIdx.x * blockDim.x + threadIdx.x;
  int i, j;
  if (e < E) {
    j = ei[e];
    i = ei[E + e];
    j = j < 0 ? 0 : (j >= n ? n - 1 : j);
    i = i < 0 ? 0 : (i >= n ? n - 1 : i);
  } else if (e < E + n) {
    i = j = e - E;          // self-loop
  } else {
    return;
  }
  int pos = atomicAdd(&cur[i], 1);
  col[rowptr[i] + pos] = j;
}

// ---------------- sentinel rows (padding contributes zero) ----------------
__global__ void k_sentinel1(float* h1, float* a_src1, int n) {
  int t = threadIdx.x;
  if (t < H1C1) h1[(size_t)n * H1C1 + t] = 0.f;
  if (t < NH1)  a_src1[n * NH1 + t] = -1e30f;
}
__global__ void k_sentinel2(bf16* h2, float* a_src2, int n) {
  int t = threadIdx.x;
  if (t < OUTC) h2[(size_t)n * OUTC + t] = __float2bfloat16(0.f);
  if (t == 0)   a_src2[n] = -1e30f;
}

// ---------------- layer 1: node transform ----------------
__global__ __launch_bounds__(256) void k_l1_transform(
    const float* __restrict__ x, const float* __restrict__ W1,
    const float* __restrict__ as1, const float* __restrict__ ad1,
    float* __restrict__ h1, float* __restrict__ a_src, float* __restrict__ a_dst,
    int n) {
  __shared__ float W1s[IN_CH * H1C1];   // 16 KB, [k*32+m]
  __shared__ float xs[8 * IN_CH];       // 4 KB
  int t = threadIdx.x;
  for (int idx = t; idx < IN_CH * H1C1; idx += 256) W1s[idx] = W1[idx];
  int base = blockIdx.x * 8;
  for (int idx = t; idx < 8 * IN_CH; idx += 256) {
    int row = idx >> 7, k = idx & 127;
    int nb = base + row;
    xs[idx] = (nb < n) ? x[(size_t)nb * IN_CH + k] : 0.f;
  }
  __syncthreads();
  int nl = t >> 5, m = t & 31;          // m = hd*8 + c
  int node = base + nl;
  float acc = 0.f;
#pragma unroll
  for (int k = 0; k < IN_CH; k++) acc += xs[nl * IN_CH + k] * W1s[k * H1C1 + m];
  float vs = acc * as1[m];
  float vd = acc * ad1[m];
  for (int off = 1; off < 8; off <<= 1) {
    vs += __shfl_xor(vs, off, 64);
    vd += __shfl_xor(vd, off, 64);
  }
  if (node < n) {
    h1[(size_t)node * H1C1 + m] = acc;
    if ((m & 7) == 0) {
      a_src[node * NH1 + (m >> 3)] = vs;
      a_dst[node * NH1 + (m >> 3)] = vd;
    }
  }
}

// ---------------- layer 1: aggregate (8-edge unrolled) ----------------
// one wave per node; lanes 0..31 & 32..63 process alternate int4 groups
__global__ __launch_bounds__(256) void k_l1_agg(
    const int* __restrict__ rowptr, const int* __restrict__ col,
    const float* __restrict__ h1, const float* __restrict__ a_src,
    const float* __restrict__ a_dst, const float* __restrict__ b1,
    float* __restrict__ h1out, int n) {
  int wid = threadIdx.x >> 6, lane = threadIdx.x & 63;
  int node = blockIdx.x * 4 + wid;
  if (node >= n) return;
  int idx = lane & 31;
  int hd = idx >> 3;
  int half = lane >> 5;
  int rs = rowptr[node], re = rowptr[node + 1];   // re-rs multiple of 8
  float adst = a_dst[node * NH1 + hd];
  float acc = 0.f, sw = 0.f;
  for (int e = rs + 4 * half; e < re; e += 8) {
    int4 j4 = *(const int4*)(col + e);
    float s0 = a_src[j4.x * NH1 + hd];
    float s1 = a_src[j4.y * NH1 + hd];
    float s2 = a_src[j4.z * NH1 + hd];
    float s3 = a_src[j4.w * NH1 + hd];
    float g0 = h1[(size_t)j4.x * H1C1 + idx];
    float g1 = h1[(size_t)j4.y * H1C1 + idx];
    float g2 = h1[(size_t)j4.z * H1C1 + idx];
    float g3 = h1[(size_t)j4.w * H1C1 + idx];
    float l0 = s0 + adst; l0 = l0 > 0.f ? l0 : NEG * l0;
    float l1 = s1 + adst; l1 = l1 > 0.f ? l1 : NEG * l1;
    float l2 = s2 + adst; l2 = l2 > 0.f ? l2 : NEG * l2;
    float l3 = s3 + adst; l3 = l3 > 0.f ? l3 : NEG * l3;
    float w0 = __expf(l0), w1 = __expf(l1), w2 = __expf(l2), w3 = __expf(l3);
    sw += (w0 + w1) + (w2 + w3);
    acc += w0 * g0; acc += w1 * g1; acc += w2 * g2; acc += w3 * g3;
  }
  acc += __shfl_down(acc, 32, 64);
  sw  += __shfl_down(sw, 32, 64);
  if (half == 0) {
    float o = acc / (sw + 1e-16f) + b1[idx];
    h1out[(size_t)node * H1C1 + idx] = fmaxf(o, 0.f);   // relu between layers
  }
}

// ---------------- layer 2: node transform ----------------
__global__ __launch_bounds__(256) void k_l2_transform(
    const float* __restrict__ h1out, const float* __restrict__ W2,
    const float* __restrict__ as2, const float* __restrict__ ad2,
    bf16* __restrict__ h2, float* __restrict__ a_src2, float* __restrict__ a_dst2,
    int n) {
  __shared__ float W2s[H1C1 * OUTC];   // 8 KB, [k*64+c]
  __shared__ float hs[4 * H1C1];
  int t = threadIdx.x;
  for (int idx = t; idx < H1C1 * OUTC; idx += 256) W2s[idx] = W2[idx];
  int base = blockIdx.x * 4;
  if (t < 4 * H1C1) {
    int row = t >> 5, k = t & 31;
    int nb = base + row;
    hs[t] = (nb < n) ? h1out[(size_t)nb * H1C1 + k] : 0.f;
  }
  __syncthreads();
  int nl = t >> 6, c = t & 63;
  int node = base + nl;
  float acc = 0.f;
#pragma unroll
  for (int k = 0; k < H1C1; k++) acc += hs[nl * H1C1 + k] * W2s[k * OUTC + c];
  float vs = acc * as2[c];
  float vd = acc * ad2[c];
  for (int off = 1; off < 64; off <<= 1) {
    vs += __shfl_xor(vs, off, 64);
    vd += __shfl_xor(vd, off, 64);
  }
  if (node < n) {
    h2[(size_t)node * OUTC + c] = __float2bfloat16(acc);
    if (c == 0) { a_src2[node] = vs; a_dst2[node] = vd; }
  }
}

// ---------------- layer 2: aggregate + output (8-edge unrolled) ----------------
__global__ __launch_bounds__(256) void k_l2_agg(
    const int* __restrict__ rowptr, const int* __restrict__ col,
    const bf16* __restrict__ h2, const float* __restrict__ a_src2,
    const float* __restrict__ a_dst2, const float* __restrict__ b2v,
    float* __restrict__ out, int n) {
  int wid = threadIdx.x >> 6, lane = threadIdx.x & 63;
  int node = blockIdx.x * 4 + wid;
  if (node >= n) return;
  int rs = rowptr[node], re = rowptr[node + 1];   // multiple of 8
  float adst = a_dst2[node];
  float acc = 0.f, sw = 0.f;
  for (int e = rs; e < re; e += 8) {
    int4 ja = *(const int4*)(col + e);
    int4 jb = *(const int4*)(col + e + 4);
    float s0 = a_src2[ja.x], s1 = a_src2[ja.y], s2 = a_src2[ja.z], s3 = a_src2[ja.w];
    float s4 = a_src2[jb.x], s5 = a_src2[jb.y], s6 = a_src2[jb.z], s7 = a_src2[jb.w];
    float g0 = b2f(h2[(size_t)ja.x * OUTC + lane]);
    float g1 = b2f(h2[(size_t)ja.y * OUTC + lane]);
    float g2 = b2f(h2[(size_t)ja.z * OUTC + lane]);
    float g3 = b2f(h2[(size_t)ja.w * OUTC + lane]);
    float g4 = b2f(h2[(size_t)jb.x * OUTC + lane]);
    float g5 = b2f(h2[(size_t)jb.y * OUTC + lane]);
    float g6 = b2f(h2[(size_t)jb.z * OUTC + lane]);
    float g7 = b2f(h2[(size_t)jb.w * OUTC + lane]);
    float l0 = s0 + adst; l0 = l0 > 0.f ? l0 : NEG * l0;
    float l1 = s1 + adst; l1 = l1 > 0.f ? l1 : NEG * l1;
    float l2 = s2 + adst; l2 = l2 > 0.f ? l2 : NEG * l2;
    float l3 = s3 + adst; l3 = l3 > 0.f ? l3 : NEG * l3;
    float l4 = s4 + adst; l4 = l4 > 0.f ? l4 : NEG * l4;
    float l5 = s5 + adst; l5 = l5 > 0.f ? l5 : NEG * l5;
    float l6 = s6 + adst; l6 = l6 > 0.f ? l6 : NEG * l6;
    float l7 = s7 + adst; l7 = l7 > 0.f ? l7 : NEG * l7;
    float w0 = __expf(l0), w1 = __expf(l1), w2 = __expf(l2), w3 = __expf(l3);
    float w4 = __expf(l4), w5 = __expf(l5), w6 = __expf(l6), w7 = __expf(l7);
    sw += ((w0 + w1) + (w2 + w3)) + ((w4 + w5) + (w6 + w7));
    acc += w0 * g0; acc += w1 * g1; acc += w2 * g2; acc += w3 * g3;
    acc += w4 * g4; acc += w5 * g5; acc += w6 * g6; acc += w7 * g7;
  }
  float o = acc / (sw + 1e-16f) + b2v[lane];
  out[(size_t)node * OUTC + lane] = o;
}

// ---------------- launch ----------------

extern "C" void kernel_launch(void* const* d_in, const int* in_sizes, int n_in,
                              void* d_out, int out_size, void* d_ws, size_t ws_size,
                              hipStream_t stream) {
  const float* x   = (const float*)d_in[0];
  const int*   ei  = (const int*)d_in[1];
  const float* W1  = (const float*)d_in[2];
  const float* as1 = (const float*)d_in[3];
  const float* ad1 = (const float*)d_in[4];
  const float* b1  = (const float*)d_in[5];
  const float* W2  = (const float*)d_in[6];
  const float* as2 = (const float*)d_in[7];
  const float* ad2 = (const float*)d_in[8];
  const float* b2  = (const float*)d_in[9];
  float* out = (float*)d_out;

  int n = in_sizes[0] / IN_CH;   // 50000
  int E = in_sizes[1] / 2;       // 1600000
  int colcap = E + RPAD * n + 16;   // upper bound on padded CSR size

  // Workspace (peak ~23 MB), phase-aliased:
  char* w = (char*)d_ws;
  auto al = [](size_t v) { return (v + 255) & ~(size_t)255; };
  size_t off = 0;
  int*   cnt    = (int*)(w + off); off += al((size_t)n * 4);        // reused as cur
  int*   rowptr = (int*)(w + off); off += al((size_t)(n + 1) * 4);
  int*   col    = (int*)(w + off); off += al((size_t)colcap * 4);
  float* h1out  = (float*)(w + off); off += al((size_t)n * H1C1 * 4);
  size_t dyn = off;
  // phase 1 (n+1 rows: last is the sentinel)
  float* h1     = (float*)(w + dyn);
  float* a_src1 = (float*)(w + dyn + al((size_t)(n + 1) * H1C1 * 4));
  float* a_dst1 = (float*)(w + dyn + al((size_t)(n + 1) * H1C1 * 4) + al((size_t)(n + 1) * NH1 * 4));
  // phase 2 (aliases phase-1 region; h1/a_src1/a_dst1 dead by then)
  bf16*  h2     = (bf16*)(w + dyn);
  float* a_src2 = (float*)(w + dyn + al((size_t)(n + 1) * OUTC * 2));
  float* a_dst2 = (float*)(w + dyn + al((size_t)(n + 1) * OUTC * 2) + al((size_t)(n + 1) * 4));
  int*   cur    = cnt;   // cnt dead after k_scan

  // CSR build (padded rows, sentinel fill)
  hipLaunchKernelGGL(k_init_cnt, dim3((n + 255) / 256), dim3(256), 0, stream, cnt, n);
  hipLaunchKernelGGL(k_hist, dim3((E + 255) / 256), dim3(256), 0, stream, ei, cnt, E, n);
  hipLaunchKernelGGL(k_scan, dim3(1), dim3(1024), 0, stream, cnt, rowptr, n);
  hipMemsetAsync(cur, 0, (size_t)n * 4, stream);
  hipLaunchKernelGGL(k_fill_col, dim3((colcap + 255) / 256), dim3(256), 0, stream,
                     col, colcap, n);
  hipLaunchKernelGGL(k_scatter, dim3((E + n + 255) / 256), dim3(256), 0, stream,
                     ei, rowptr, cur, col, E, n);

  // layer 1
  hipLaunchKernelGGL(k_l1_transform, dim3((n + 7) / 8), dim3(256), 0, stream,
                     x, W1, as1, ad1, h1, a_src1, a_dst1, n);
  hipLaunchKernelGGL(k_sentinel1, dim3(1), dim3(64), 0, stream, h1, a_src1, n);
  hipLaunchKernelGGL(k_l1_agg, dim3((n + 3) / 4), dim3(256), 0, stream,
                     rowptr, col, h1, a_src1, a_dst1, b1, h1out, n);

  // layer 2
  hipLaunchKernelGGL(k_l2_transform, dim3((n + 3) / 4), dim3(256), 0, stream,
                     h1out, W2, as2, ad2, h2, a_src2, a_dst2, n);
  hipLaunchKernelGGL(k_sentinel2, dim3(1), dim3(64), 0, stream, h2, a_src2, n);
  hipLaunchKernelGGL(k_l2_agg, dim3((n + 3) / 4), dim3(256), 0, stream,
                     rowptr, col, h2, a_src2, a_dst2, b2, out, n);
}

// Round 4
// 306.237 us; speedup vs baseline: 1.9614x; 1.4403x over previous
//
#include <hip/hip_runtime.h>
#include <hip/hip_bf16.h>

#define IN_CH 128
#define H1C1  32    // heads1 * c1
#define NH1   4
#define OUTC  64
#define NEG   0.2f
#define RPAD  8     // CSR row padding (int4 loads + 8-deep ILP)
#define BSH   6
#define BSZ   64    // nodes per bucket
#define NBMAX 1024  // supports n <= 65536 (pack requires n < 65536 too)
#define CHUNK 4096  // edges per workgroup in binning

typedef __hip_bfloat16 bf16;
typedef unsigned int u32;
__device__ __forceinline__ float b2f(bf16 v) { return __bfloat162float(v); }

// ---------------- CSR build: two-level LDS-binned counting sort ----------------

// pass A0: per-bucket raw totals (incl. self-loops)
__global__ __launch_bounds__(256) void k_bin_count(
    const int* __restrict__ ei, int* __restrict__ bucket_tot, int E, int n, int nb) {
  __shared__ int cnt[NBMAX];
  int t = threadIdx.x;
  for (int b = t; b < nb; b += 256) cnt[b] = 0;
  __syncthreads();
  long base = (long)blockIdx.x * CHUNK;
  long total = (long)E + n;
#pragma unroll
  for (int i = 0; i < CHUNK / 256; i++) {
    long e = base + i * 256 + t;
    if (e < total) {
      int d = (e < E) ? ei[E + e] : (int)(e - E);
      d = d < 0 ? 0 : (d >= n ? n - 1 : d);
      atomicAdd(&cnt[d >> BSH], 1);
    }
  }
  __syncthreads();
  for (int b = t; b < nb; b += 256) {
    int c = cnt[b];
    if (c) atomicAdd(&bucket_tot[b], c);
  }
}

// single-wave exclusive scan of nb (<=1024) values
__global__ __launch_bounds__(64) void k_scan_sm(const int* __restrict__ src,
                                                int* __restrict__ dst,
                                                int nb, int* __restrict__ total_out) {
  int lane = threadIdx.x;
  int carry = 0;
  for (int base = 0; base < nb; base += 64) {
    int i = base + lane;
    int v = (i < nb) ? src[i] : 0;
    int orig = v;
    for (int off = 1; off < 64; off <<= 1) {
      int u = __shfl_up(v, off, 64);
      if (lane >= off) v += u;
    }
    if (i < nb) dst[i] = carry + v - orig;
    carry += __shfl(v, 63, 64);
  }
  if (lane == 0 && total_out) *total_out = carry;
}

// pass A: bin edges into bucket-major packed array, LDS-staged coalesced flush
__global__ __launch_bounds__(256) void k_bin(
    const int* __restrict__ ei, const int* __restrict__ bucket_start,
    int* __restrict__ bucket_fill, u32* __restrict__ data,
    int E, int n, int nb) {
  __shared__ int cnt[NBMAX];
  __shared__ int lbase[NBMAX];
  __shared__ int gbase[NBMAX];
  __shared__ u32 staged[CHUNK];
  int t = threadIdx.x;
  int lane = t & 63, wid = t >> 6;
  for (int b = t; b < nb; b += 256) cnt[b] = 0;
  __syncthreads();
  long base = (long)blockIdx.x * CHUNK;
  long totE = (long)E + n;
  u32 pk[CHUNK / 256];
  int bk[CHUNK / 256];
#pragma unroll
  for (int i = 0; i < CHUNK / 256; i++) {
    long e = base + i * 256 + t;
    if (e < totE) {
      int j, d;
      if (e < E) {
        j = ei[e]; d = ei[E + e];
        j = j < 0 ? 0 : (j >= n ? n - 1 : j);
        d = d < 0 ? 0 : (d >= n ? n - 1 : d);
      } else { j = d = (int)(e - E); }
      bk[i] = d >> BSH;
      pk[i] = ((u32)d << 16) | (u32)j;
      atomicAdd(&cnt[bk[i]], 1);
    } else bk[i] = -1;
  }
  __syncthreads();
  if (wid == 0) {                       // exclusive scan cnt -> lbase
    int carry = 0;
    for (int b0 = 0; b0 < nb; b0 += 64) {
      int i = b0 + lane;
      int v = (i < nb) ? cnt[i] : 0;
      int orig = v;
      for (int off = 1; off < 64; off <<= 1) {
        int u = __shfl_up(v, off, 64);
        if (lane >= off) v += u;
      }
      if (i < nb) lbase[i] = carry + v - orig;
      carry += __shfl(v, 63, 64);
    }
  }
  __syncthreads();
  for (int b = t; b < nb; b += 256) {   // reserve global space, reset cnt
    int c = cnt[b];
    gbase[b] = c ? atomicAdd(&bucket_fill[b], c) : 0;
    cnt[b] = 0;
  }
  __syncthreads();
#pragma unroll
  for (int i = 0; i < CHUNK / 256; i++) {
    if (bk[i] >= 0) {
      int loc = atomicAdd(&cnt[bk[i]], 1);
      staged[lbase[bk[i]] + loc] = pk[i];
    }
  }
  __syncthreads();
  long remL = totE - base;
  int rem = remL > CHUNK ? CHUNK : (int)remL;
  for (int idx = t; idx < rem; idx += 256) {   // coalesced-run flush
    u32 p = staged[idx];
    int b = (int)(p >> 16) >> BSH;
    int pos = bucket_start[b] + gbase[b] + (idx - lbase[b]);
    data[pos] = p;
  }
}

// pass B1: padded degree total per bucket
__global__ __launch_bounds__(256) void k_bucket_deg(
    const u32* __restrict__ data, const int* __restrict__ bucket_start,
    const int* __restrict__ bucket_tot, int* __restrict__ padded_tot,
    int n, int nb) {
  __shared__ int c64[BSZ];
  int t = threadIdx.x;
  int b = blockIdx.x;
  if (t < BSZ) c64[t] = 0;
  __syncthreads();
  int s = bucket_start[b], cnt = bucket_tot[b];
  for (int i = t; i < cnt; i += 256)
    atomicAdd(&c64[(data[s + i] >> 16) & (BSZ - 1)], 1);
  __syncthreads();
  if (t < 64) {
    int pt = (c64[t] + RPAD - 1) & ~(RPAD - 1);
    for (int off = 1; off < 64; off <<= 1) pt += __shfl_xor(pt, off, 64);
    if (t == 0) padded_tot[b] = pt;
  }
}

// pass B2: rowptr + scatter col within this bucket's contiguous region + pad fill
__global__ __launch_bounds__(256) void k_bucket_scatter(
    const u32* __restrict__ data, const int* __restrict__ bucket_start,
    const int* __restrict__ bucket_tot, const int* __restrict__ rbase,
    int* __restrict__ rowptr, int* __restrict__ col, int n, int nb) {
  __shared__ int cur[BSZ];
  __shared__ int rp[BSZ];
  int t = threadIdx.x;
  int b = blockIdx.x;
  if (t < BSZ) cur[t] = 0;
  __syncthreads();
  int s = bucket_start[b], cnt = bucket_tot[b];
  for (int i = t; i < cnt; i += 256)
    atomicAdd(&cur[(data[s + i] >> 16) & (BSZ - 1)], 1);
  __syncthreads();
  if (t < 64) {                         // padded exclusive scan within bucket
    int c = cur[t];
    int v = (c + RPAD - 1) & ~(RPAD - 1);
    int orig = v;
    for (int off = 1; off < 64; off <<= 1) {
      int u = __shfl_up(v, off, 64);
      if (t >= off) v += u;
    }
    int r = rbase[b] + v - orig;
    rp[t] = r;
    cur[t] = r;
    int node = (b << BSH) + t;
    if (node < n) rowptr[node] = r;
  }
  __syncthreads();
  for (int i = t; i < cnt; i += 256) {
    u32 p = data[s + i];
    int dl = (int)(p >> 16) & (BSZ - 1);
    int pos = atomicAdd(&cur[dl], 1);
    col[pos] = (int)(p & 0xFFFFu);
  }
  __syncthreads();
  if (t < 64) {                         // sentinel-fill pad slots
    int c = cur[t];
    int raw = c - rp[t];
    int end = rp[t] + ((raw + RPAD - 1) & ~(RPAD - 1));
    for (int k = c; k < end; k++) col[k] = n;
  }
}

// ---------------- sentinel rows (padding contributes zero) ----------------
__global__ void k_sentinel1(float* h1, float* a_src1, int n) {
  int t = threadIdx.x;
  if (t < H1C1) h1[(size_t)n * H1C1 + t] = 0.f;
  if (t < NH1)  a_src1[n * NH1 + t] = -1e30f;
}
__global__ void k_sentinel2(bf16* h2, float* a_src2, int n) {
  int t = threadIdx.x;
  if (t < OUTC) h2[(size_t)n * OUTC + t] = __float2bfloat16(0.f);
  if (t == 0)   a_src2[n] = -1e30f;
}

// ---------------- layer 1: node transform ----------------
__global__ __launch_bounds__(256) void k_l1_transform(
    const float* __restrict__ x, const float* __restrict__ W1,
    const float* __restrict__ as1, const float* __restrict__ ad1,
    float* __restrict__ h1, float* __restrict__ a_src, float* __restrict__ a_dst,
    int n) {
  __shared__ float W1s[IN_CH * H1C1];   // 16 KB
  __shared__ float xs[8 * IN_CH];       // 4 KB
  int t = threadIdx.x;
  for (int idx = t; idx < IN_CH * H1C1; idx += 256) W1s[idx] = W1[idx];
  int base = blockIdx.x * 8;
  for (int idx = t; idx < 8 * IN_CH; idx += 256) {
    int row = idx >> 7, k = idx & 127;
    int nb = base + row;
    xs[idx] = (nb < n) ? x[(size_t)nb * IN_CH + k] : 0.f;
  }
  __syncthreads();
  int nl = t >> 5, m = t & 31;          // m = hd*8 + c
  int node = base + nl;
  float acc = 0.f;
#pragma unroll
  for (int k = 0; k < IN_CH; k++) acc += xs[nl * IN_CH + k] * W1s[k * H1C1 + m];
  float vs = acc * as1[m];
  float vd = acc * ad1[m];
  for (int off = 1; off < 8; off <<= 1) {
    vs += __shfl_xor(vs, off, 64);
    vd += __shfl_xor(vd, off, 64);
  }
  if (node < n) {
    h1[(size_t)node * H1C1 + m] = acc;
    if ((m & 7) == 0) {
      a_src[node * NH1 + (m >> 3)] = vs;
      a_dst[node * NH1 + (m >> 3)] = vd;
    }
  }
}

// ---------------- layer 1: aggregate (8-edge unrolled) ----------------
__global__ __launch_bounds__(256) void k_l1_agg(
    const int* __restrict__ rowptr, const int* __restrict__ col,
    const float* __restrict__ h1, const float* __restrict__ a_src,
    const float* __restrict__ a_dst, const float* __restrict__ b1,
    float* __restrict__ h1out, int n) {
  int wid = threadIdx.x >> 6, lane = threadIdx.x & 63;
  int node = blockIdx.x * 4 + wid;
  if (node >= n) return;
  int idx = lane & 31;
  int hd = idx >> 3;
  int half = lane >> 5;
  int rs = rowptr[node], re = rowptr[node + 1];
  float adst = a_dst[node * NH1 + hd];
  float acc = 0.f, sw = 0.f;
  for (int e = rs + 4 * half; e < re; e += 8) {
    int4 j4 = *(const int4*)(col + e);
    float s0 = a_src[j4.x * NH1 + hd];
    float s1 = a_src[j4.y * NH1 + hd];
    float s2 = a_src[j4.z * NH1 + hd];
    float s3 = a_src[j4.w * NH1 + hd];
    float g0 = h1[(size_t)j4.x * H1C1 + idx];
    float g1 = h1[(size_t)j4.y * H1C1 + idx];
    float g2 = h1[(size_t)j4.z * H1C1 + idx];
    float g3 = h1[(size_t)j4.w * H1C1 + idx];
    float l0 = s0 + adst; l0 = l0 > 0.f ? l0 : NEG * l0;
    float l1 = s1 + adst; l1 = l1 > 0.f ? l1 : NEG * l1;
    float l2 = s2 + adst; l2 = l2 > 0.f ? l2 : NEG * l2;
    float l3 = s3 + adst; l3 = l3 > 0.f ? l3 : NEG * l3;
    float w0 = __expf(l0), w1 = __expf(l1), w2 = __expf(l2), w3 = __expf(l3);
    sw += (w0 + w1) + (w2 + w3);
    acc += w0 * g0; acc += w1 * g1; acc += w2 * g2; acc += w3 * g3;
  }
  acc += __shfl_down(acc, 32, 64);
  sw  += __shfl_down(sw, 32, 64);
  if (half == 0) {
    float o = acc / (sw + 1e-16f) + b1[idx];
    h1out[(size_t)node * H1C1 + idx] = fmaxf(o, 0.f);
  }
}

// ---------------- layer 2: node transform ----------------
__global__ __launch_bounds__(256) void k_l2_transform(
    const float* __restrict__ h1out, const float* __restrict__ W2,
    const float* __restrict__ as2, const float* __restrict__ ad2,
    bf16* __restrict__ h2, float* __restrict__ a_src2, float* __restrict__ a_dst2,
    int n) {
  __shared__ float W2s[H1C1 * OUTC];   // 8 KB
  __shared__ float hs[4 * H1C1];
  int t = threadIdx.x;
  for (int idx = t; idx < H1C1 * OUTC; idx += 256) W2s[idx] = W2[idx];
  int base = blockIdx.x * 4;
  if (t < 4 * H1C1) {
    int row = t >> 5, k = t & 31;
    int nb = base + row;
    hs[t] = (nb < n) ? h1out[(size_t)nb * H1C1 + k] : 0.f;
  }
  __syncthreads();
  int nl = t >> 6, c = t & 63;
  int node = base + nl;
  float acc = 0.f;
#pragma unroll
  for (int k = 0; k < H1C1; k++) acc += hs[nl * H1C1 + k] * W2s[k * OUTC + c];
  float vs = acc * as2[c];
  float vd = acc * ad2[c];
  for (int off = 1; off < 64; off <<= 1) {
    vs += __shfl_xor(vs, off, 64);
    vd += __shfl_xor(vd, off, 64);
  }
  if (node < n) {
    h2[(size_t)node * OUTC + c] = __float2bfloat16(acc);
    if (c == 0) { a_src2[node] = vs; a_dst2[node] = vd; }
  }
}

// ---------------- layer 2: aggregate + output (8-edge unrolled) ----------------
__global__ __launch_bounds__(256) void k_l2_agg(
    const int* __restrict__ rowptr, const int* __restrict__ col,
    const bf16* __restrict__ h2, const float* __restrict__ a_src2,
    const float* __restrict__ a_dst2, const float* __restrict__ b2v,
    float* __restrict__ out, int n) {
  int wid = threadIdx.x >> 6, lane = threadIdx.x & 63;
  int node = blockIdx.x * 4 + wid;
  if (node >= n) return;
  int rs = rowptr[node], re = rowptr[node + 1];
  float adst = a_dst2[node];
  float acc = 0.f, sw = 0.f;
  for (int e = rs; e < re; e += 8) {
    int4 ja = *(const int4*)(col + e);
    int4 jb = *(const int4*)(col + e + 4);
    float s0 = a_src2[ja.x], s1 = a_src2[ja.y], s2 = a_src2[ja.z], s3 = a_src2[ja.w];
    float s4 = a_src2[jb.x], s5 = a_src2[jb.y], s6 = a_src2[jb.z], s7 = a_src2[jb.w];
    float g0 = b2f(h2[(size_t)ja.x * OUTC + lane]);
    float g1 = b2f(h2[(size_t)ja.y * OUTC + lane]);
    float g2 = b2f(h2[(size_t)ja.z * OUTC + lane]);
    float g3 = b2f(h2[(size_t)ja.w * OUTC + lane]);
    float g4 = b2f(h2[(size_t)jb.x * OUTC + lane]);
    float g5 = b2f(h2[(size_t)jb.y * OUTC + lane]);
    float g6 = b2f(h2[(size_t)jb.z * OUTC + lane]);
    float g7 = b2f(h2[(size_t)jb.w * OUTC + lane]);
    float l0 = s0 + adst; l0 = l0 > 0.f ? l0 : NEG * l0;
    float l1 = s1 + adst; l1 = l1 > 0.f ? l1 : NEG * l1;
    float l2 = s2 + adst; l2 = l2 > 0.f ? l2 : NEG * l2;
    float l3 = s3 + adst; l3 = l3 > 0.f ? l3 : NEG * l3;
    float l4 = s4 + adst; l4 = l4 > 0.f ? l4 : NEG * l4;
    float l5 = s5 + adst; l5 = l5 > 0.f ? l5 : NEG * l5;
    float l6 = s6 + adst; l6 = l6 > 0.f ? l6 : NEG * l6;
    float l7 = s7 + adst; l7 = l7 > 0.f ? l7 : NEG * l7;
    float w0 = __expf(l0), w1 = __expf(l1), w2 = __expf(l2), w3 = __expf(l3);
    float w4 = __expf(l4), w5 = __expf(l5), w6 = __expf(l6), w7 = __expf(l7);
    sw += ((w0 + w1) + (w2 + w3)) + ((w4 + w5) + (w6 + w7));
    acc += w0 * g0; acc += w1 * g1; acc += w2 * g2; acc += w3 * g3;
    acc += w4 * g4; acc += w5 * g5; acc += w6 * g6; acc += w7 * g7;
  }
  float o = acc / (sw + 1e-16f) + b2v[lane];
  out[(size_t)node * OUTC + lane] = o;
}

// ---------------- launch ----------------

extern "C" void kernel_launch(void* const* d_in, const int* in_sizes, int n_in,
                              void* d_out, int out_size, void* d_ws, size_t ws_size,
                              hipStream_t stream) {
  const float* x   = (const float*)d_in[0];
  const int*   ei  = (const int*)d_in[1];
  const float* W1  = (const float*)d_in[2];
  const float* as1 = (const float*)d_in[3];
  const float* ad1 = (const float*)d_in[4];
  const float* b1  = (const float*)d_in[5];
  const float* W2  = (const float*)d_in[6];
  const float* as2 = (const float*)d_in[7];
  const float* ad2 = (const float*)d_in[8];
  const float* b2  = (const float*)d_in[9];
  float* out = (float*)d_out;

  int n = in_sizes[0] / IN_CH;     // 50000 (pack requires n < 65536)
  int E = in_sizes[1] / 2;         // 1600000
  int nb = (n + BSZ - 1) >> BSH;   // 782
  long tot = (long)E + n;
  int nA = (int)((tot + CHUNK - 1) / CHUNK);
  int colcap = E + RPAD * n + 16;

  char* w = (char*)d_ws;
  auto al = [](size_t v) { return (v + 255) & ~(size_t)255; };
  size_t off = 0;
  int* bucket_tot   = (int*)(w + off); off += al((size_t)nb * 4);
  int* bucket_start = (int*)(w + off); off += al((size_t)nb * 4);
  int* bucket_fill  = (int*)(w + off); off += al((size_t)nb * 4);
  int* padded_tot   = (int*)(w + off); off += al((size_t)nb * 4);
  int* rbase        = (int*)(w + off); off += al((size_t)nb * 4);
  int* rowptr       = (int*)(w + off); off += al((size_t)(n + 1) * 4);
  u32* data         = (u32*)(w + off);
  float* h1out      = (float*)data;    // alias: data dead before h1out written
  off += al((size_t)tot * 4 > (size_t)n * H1C1 * 4 ? (size_t)tot * 4
                                                   : (size_t)n * H1C1 * 4);
  int* col          = (int*)(w + off); off += al((size_t)colcap * 4);
  size_t dyn = off;
  // phase 1 (n+1 rows: last is sentinel)
  float* h1     = (float*)(w + dyn);
  float* a_src1 = (float*)(w + dyn + al((size_t)(n + 1) * H1C1 * 4));
  float* a_dst1 = (float*)(w + dyn + al((size_t)(n + 1) * H1C1 * 4) + al((size_t)(n + 1) * NH1 * 4));
  // phase 2 (aliases phase-1 region)
  bf16*  h2     = (bf16*)(w + dyn);
  float* a_src2 = (float*)(w + dyn + al((size_t)(n + 1) * OUTC * 2));
  float* a_dst2 = (float*)(w + dyn + al((size_t)(n + 1) * OUTC * 2) + al((size_t)(n + 1) * 4));

  // ---- CSR build ----
  hipMemsetAsync(bucket_tot, 0, (size_t)nb * 4, stream);
  hipMemsetAsync(bucket_fill, 0, (size_t)nb * 4, stream);
  hipLaunchKernelGGL(k_bin_count, dim3(nA), dim3(256), 0, stream, ei, bucket_tot, E, n, nb);
  hipLaunchKernelGGL(k_scan_sm, dim3(1), dim3(64), 0, stream,
                     bucket_tot, bucket_start, nb, (int*)nullptr);
  hipLaunchKernelGGL(k_bin, dim3(nA), dim3(256), 0, stream,
                     ei, bucket_start, bucket_fill, data, E, n, nb);
  hipLaunchKernelGGL(k_bucket_deg, dim3(nb), dim3(256), 0, stream,
                     data, bucket_start, bucket_tot, padded_tot, n, nb);
  hipLaunchKernelGGL(k_scan_sm, dim3(1), dim3(64), 0, stream,
                     padded_tot, rbase, nb, rowptr + n);
  hipLaunchKernelGGL(k_bucket_scatter, dim3(nb), dim3(256), 0, stream,
                     data, bucket_start, bucket_tot, rbase, rowptr, col, n, nb);

  // ---- layer 1 ----
  hipLaunchKernelGGL(k_l1_transform, dim3((n + 7) / 8), dim3(256), 0, stream,
                     x, W1, as1, ad1, h1, a_src1, a_dst1, n);
  hipLaunchKernelGGL(k_sentinel1, dim3(1), dim3(64), 0, stream, h1, a_src1, n);
  hipLaunchKernelGGL(k_l1_agg, dim3((n + 3) / 4), dim3(256), 0, stream,
                     rowptr, col, h1, a_src1, a_dst1, b1, h1out, n);

  // ---- layer 2 ----
  hipLaunchKernelGGL(k_l2_transform, dim3((n + 3) / 4), dim3(256), 0, stream,
                     h1out, W2, as2, ad2, h2, a_src2, a_dst2, n);
  hipLaunchKernelGGL(k_sentinel2, dim3(1), dim3(64), 0, stream, h2, a_src2, n);
  hipLaunchKernelGGL(k_l2_agg, dim3((n + 3) / 4), dim3(256), 0, stream,
                     rowptr, col, h2, a_src2, a_dst2, b2, out, n);
}